// Round 2
// baseline (7407.426 us; speedup 1.0000x reference)
//
#include <hip/hip_runtime.h>
#include <hip/hip_bf16.h>
#include <math.h>

#define B_ 256
#define L_ 512
#define V_ 256
#define E_ 256
#define H_ 1024

typedef float  f32x4  __attribute__((ext_vector_type(4)));
typedef short  bf16x8 __attribute__((ext_vector_type(8)));

static __device__ __forceinline__ ushort f2bf(float v) {
    __hip_bfloat16 b = __float2bfloat16(v);
    return *reinterpret_cast<ushort*>(&b);
}

static __device__ __forceinline__ void load_lds16(const void* g, void* l) {
    __builtin_amdgcn_global_load_lds(
        (const __attribute__((address_space(1))) void*)(g),
        (__attribute__((address_space(3))) void*)(l), 16, 0, 0);
}

// ---------- prep: transpose f32 [R][C] -> bf16 [C][R] ----------
__global__ void k_transpose_bf16(const float* __restrict__ in, ushort* __restrict__ out,
                                 int R, int C) {
    __shared__ float tile[64][65];
    int bx = blockIdx.x;           // over C/64
    int by = blockIdx.y;           // over R/64
    int tid = threadIdx.x;
    int g = tid >> 6, l = tid & 63;
    for (int i = 0; i < 16; ++i) {
        int r = g * 16 + i;
        tile[r][l] = in[(size_t)(by * 64 + r) * C + bx * 64 + l];
    }
    __syncthreads();
    for (int i = 0; i < 16; ++i) {
        int c = g * 16 + i;
        out[(size_t)(bx * 64 + c) * R + by * 64 + l] = f2bf(tile[l][c]);
    }
}

// ---------- prep: f32 -> bf16 copy ----------
__global__ void k_f32_to_bf16(const float* __restrict__ in, ushort* __restrict__ out, int n) {
    int i = blockIdx.x * blockDim.x + threadIdx.x;
    if (i < n) out[i] = f2bf(in[i]);
}

// ---------- prep: zero the flag array ----------
__global__ void k_zero(unsigned* __restrict__ p, int n) {
    int i = blockIdx.x * blockDim.x + threadIdx.x;
    if (i < n) p[i] = 0u;
}

// ---------- prep: proj[t][h] = sum_e emb[t][e] * W_e[e][h]  (f32) ----------
__global__ void k_proj(const float* __restrict__ emb, const float* __restrict__ We,
                       float* __restrict__ proj) {
    __shared__ float er[E_];
    int t = blockIdx.x;
    int h = blockIdx.y * 256 + threadIdx.x;
    er[threadIdx.x] = emb[t * E_ + threadIdx.x];   // blockDim.x == 256 == E_
    __syncthreads();
    float acc = 0.f;
#pragma unroll 8
    for (int e = 0; e < E_; ++e) acc += er[e] * We[(size_t)e * H_ + h];
    proj[(size_t)t * H_ + h] = acc;
}

// ---------- persistent scan kernel ----------
// 256 blocks, 1 per CU (132KB LDS). Block (rg=bid&7, cg=bid>>3) owns the 32x32
// h-tile rows [rg*32,+32) x cols [cg*32,+32). Groups of 32 blocks (same rg) are
// closed dependency sets: per-group 32-block barrier per step via flags[rg*512+s].
// W_h^T slice persists in LDS across all 512 steps. h exchanged via 2-slot ring.
__global__ __launch_bounds__(256, 1) void k_scan(
    const int* __restrict__ x, const float* __restrict__ proj,
    const ushort* __restrict__ WhT, const ushort* __restrict__ WoT,
    ushort* __restrict__ ring, float* __restrict__ logits,
    float* __restrict__ final_h, unsigned* __restrict__ flags)
{
    __shared__ ushort lds_w[32 * 1024];   // W_h^T rows c0..c0+32, swizzled (64KB), persistent
    __shared__ ushort lds_h[32 * 1024];   // H_s rows r0..r0+32, swizzled (64KB), per step
    __shared__ float  red[4 * 64 * 4];    // B-phase cross-wave reduce (4KB)

    int tid = threadIdx.x;
    int w = tid >> 6, lane = tid & 63;
    int l15 = lane & 15, l4 = lane >> 4;
    int bid = blockIdx.x;
    int rg = bid & 7;             // row-group (XCD-locality heuristic; not required for correctness)
    int cg = bid >> 3;            // 0..31 col-group
    int r0 = rg * 32, c0 = cg * 32;

    // --- preload W slice once (drained by the first __syncthreads below)
    {
        const char* wsrc = (const char*)(WhT + (size_t)c0 * H_);
        char* wd = (char*)lds_w;
        for (int i = 0; i < 16; ++i) {
            int chunk = (w * 16 + i) * 1024;
            int o = chunk + lane * 16;
            int row = o >> 11, b = o & 2047;
            int so = row * 2048 + (b ^ ((row & 7) << 4));
            load_lds16(wsrc + so, wd + chunk);
        }
    }

    // A-phase constants
    int a = w >> 1, bc = w & 1;
    int arow = a * 16 + l15;
    int brow = bc * 16 + l15;
    const char* ha = (const char*)lds_h + arow * 2048;
    const char* wa = (const char*)lds_w + brow * 2048;
    int as = (arow & 7) << 4, bs = (brow & 7) << 4;
    int gcol = c0 + bc * 16 + l15;

    // B-phase constants: group covers logits rows [r0,r0+32) x V; this block does
    // a 16x16 tile: rows r0 + (cg&1)*16.., vocab cols (cg>>1)*16..
    int lrg = cg & 1, vcol0 = (cg >> 1) * 16;
    int srow = lrg * 16 + l15;
    const char* hb = (const char*)lds_h + srow * 2048;
    int hs2 = (srow & 7) << 4;
    const ushort* wo = WoT + (size_t)(vcol0 + l15) * H_;

    for (int s = 0; s <= L_; ++s) {
        // --- wait for H_s (all group peers wrote it at step s-1)
        if (s > 0) {
            if (tid == 0) {
                while (atomicAdd(&flags[rg * 512 + (s - 1)], 0u) < 32u)
                    __builtin_amdgcn_s_sleep(8);
                __threadfence();   // acquire: invalidate stale cached copies
            }
        }
        __syncthreads();           // also guarantees B-phase (s-1) done reading lds_h

        // --- stage H_s rows [r0,r0+32) from ring slot s&1, swizzled
        {
            const char* hsrc = (const char*)(ring + (size_t)(s & 1) * B_ * H_ + (size_t)r0 * H_);
            char* hd = (char*)lds_h;
            for (int i = 0; i < 16; ++i) {
                int chunk = (w * 16 + i) * 1024;
                int o = chunk + lane * 16;
                int row = o >> 11, b = o & 2047;
                int so = row * 2048 + (b ^ ((row & 7) << 4));
                load_lds16(hsrc + so, hd + chunk);
            }
        }
        asm volatile("s_waitcnt vmcnt(0)" ::: "memory");
        __syncthreads();

        // --- A phase: H_{s+1} tile = tanh(proj[x[:,s]] + H_s @ W_h)
        if (s < L_) {
            f32x4 acc = {0.f, 0.f, 0.f, 0.f};
#pragma unroll
            for (int kk = 0; kk < 32; ++kk) {
                int kb = (kk * 32 + l4 * 8) * 2;
                bf16x8 af = *(const bf16x8*)(ha + (kb ^ as));
                bf16x8 bf = *(const bf16x8*)(wa + (kb ^ bs));
                acc = __builtin_amdgcn_mfma_f32_16x16x32_bf16(af, bf, acc, 0, 0, 0);
            }
            ushort* hnext = ring + (size_t)((s + 1) & 1) * B_ * H_;
#pragma unroll
            for (int j = 0; j < 4; ++j) {
                int grow = r0 + a * 16 + l4 * 4 + j;
                int xv = x[grow * L_ + s];
                float z = acc[j] + proj[(size_t)xv * H_ + gcol];
                float hv = tanhf(z);
                hnext[(size_t)grow * H_ + gcol] = f2bf(hv);
                if (s == L_ - 1) final_h[(size_t)grow * H_ + gcol] = hv;
            }
            __syncthreads();       // drains all waves' vmcnt before the release
            if (tid == 0) {
                __threadfence();   // release: write back dirty h lines
                atomicAdd(&flags[rg * 512 + s], 1u);
            }
        }

        // --- B phase (off critical path): logits[:, s-1] from lds_h = H_s
        if (s > 0) {
            f32x4 lacc = {0.f, 0.f, 0.f, 0.f};
#pragma unroll
            for (int kk = 0; kk < 8; ++kk) {
                int k = w * 256 + kk * 32 + l4 * 8;
                bf16x8 af = *(const bf16x8*)(hb + ((2 * k) ^ hs2));
                bf16x8 bf = *(const bf16x8*)(wo + k);
                lacc = __builtin_amdgcn_mfma_f32_16x16x32_bf16(af, bf, lacc, 0, 0, 0);
            }
#pragma unroll
            for (int j = 0; j < 4; ++j) red[(w * 64 + lane) * 4 + j] = lacc[j];
            __syncthreads();
            if (w == 0) {
                int growb = r0 + lrg * 16 + l4 * 4;
#pragma unroll
                for (int j = 0; j < 4; ++j) {
                    float ssum = red[(0 * 64 + lane) * 4 + j] + red[(1 * 64 + lane) * 4 + j]
                               + red[(2 * 64 + lane) * 4 + j] + red[(3 * 64 + lane) * 4 + j];
                    logits[((size_t)(growb + j) * L_ + (s - 1)) * V_ + vcol0 + l15] = ssum;
                }
            }
        }
    }
}

extern "C" void kernel_launch(void* const* d_in, const int* in_sizes, int n_in,
                              void* d_out, int out_size, void* d_ws, size_t ws_size,
                              hipStream_t stream)
{
    const int*   x   = (const int*)d_in[0];
    const float* hid = (const float*)d_in[1];
    const float* emb = (const float*)d_in[2];
    const float* We  = (const float*)d_in[3];
    const float* Wh  = (const float*)d_in[4];
    const float* Wo  = (const float*)d_in[5];

    float* logits  = (float*)d_out;                       // [B][L][V] f32
    float* final_h = logits + (size_t)B_ * L_ * V_;       // [B][H] f32

    char* ws = (char*)d_ws;
    float*    proj  = (float*)(ws);                                   // 1 MB   f32 [V][H]
    ushort*   WhT   = (ushort*)(ws + (1u << 20));                     // 2 MB   bf16 [H][H]^T
    ushort*   WoT   = (ushort*)(ws + 3u * (1u << 20));                // 0.5 MB bf16 [V][H]^T
    ushort*   ring  = (ushort*)(ws + 3u * (1u << 20) + (1u << 19));   // 1 MB   bf16 2x[B][H]
    unsigned* flags = (unsigned*)(ws + 4u * (1u << 20) + (1u << 19)); // 16 KB  u32 [8][512]

    // prep (stream-ordered before the persistent kernel)
    k_zero<<<dim3(16), 256, 0, stream>>>(flags, 8 * 512);
    k_transpose_bf16<<<dim3(16, 16), 256, 0, stream>>>(Wh, WhT, H_, H_);
    k_transpose_bf16<<<dim3(4, 16),  256, 0, stream>>>(Wo, WoT, H_, V_);
    k_f32_to_bf16<<<dim3(1024), 256, 0, stream>>>(hid, ring, B_ * H_);   // H_0 -> slot 0
    k_proj<<<dim3(256, 4), 256, 0, stream>>>(emb, We, proj);

    // one persistent kernel does all 512 steps + fused logits
    k_scan<<<dim3(256), 256, 0, stream>>>(x, proj, WhT, WoT, ring,
                                          logits, final_h, flags);
}

// Round 3
// 2236.836 us; speedup vs baseline: 3.3116x; 3.3116x over previous
//
#include <hip/hip_runtime.h>
#include <hip/hip_bf16.h>
#include <math.h>

#define B_ 256
#define L_ 512
#define V_ 256
#define E_ 256
#define H_ 1024

typedef float  f32x4  __attribute__((ext_vector_type(4)));
typedef short  bf16x8 __attribute__((ext_vector_type(8)));

static __device__ __forceinline__ ushort f2bf(float v) {
    __hip_bfloat16 b = __float2bfloat16(v);
    return *reinterpret_cast<ushort*>(&b);
}

static __device__ __forceinline__ void load_lds16(const void* g, void* l) {
    __builtin_amdgcn_global_load_lds(
        (const __attribute__((address_space(1))) void*)(g),
        (__attribute__((address_space(3))) void*)(l), 16, 0, 0);
}

// ---------- prep: transpose f32 [R][C] -> bf16 [C][R] ----------
__global__ void k_transpose_bf16(const float* __restrict__ in, ushort* __restrict__ out,
                                 int R, int C) {
    __shared__ float tile[64][65];
    int bx = blockIdx.x;           // over C/64
    int by = blockIdx.y;           // over R/64
    int tid = threadIdx.x;
    int g = tid >> 6, l = tid & 63;
    for (int i = 0; i < 16; ++i) {
        int r = g * 16 + i;
        tile[r][l] = in[(size_t)(by * 64 + r) * C + bx * 64 + l];
    }
    __syncthreads();
    for (int i = 0; i < 16; ++i) {
        int c = g * 16 + i;
        out[(size_t)(bx * 64 + c) * R + by * 64 + l] = f2bf(tile[l][c]);
    }
}

// ---------- prep: f32 -> bf16 copy ----------
__global__ void k_f32_to_bf16(const float* __restrict__ in, ushort* __restrict__ out, int n) {
    int i = blockIdx.x * blockDim.x + threadIdx.x;
    if (i < n) out[i] = f2bf(in[i]);
}

// ---------- prep: zero the flag array ----------
__global__ void k_zero(unsigned* __restrict__ p, int n) {
    int i = blockIdx.x * blockDim.x + threadIdx.x;
    if (i < n) p[i] = 0u;
}

// ---------- prep: proj[t][h] = sum_e emb[t][e] * W_e[e][h]  (f32) ----------
__global__ void k_proj(const float* __restrict__ emb, const float* __restrict__ We,
                       float* __restrict__ proj) {
    __shared__ float er[E_];
    int t = blockIdx.x;
    int h = blockIdx.y * 256 + threadIdx.x;
    er[threadIdx.x] = emb[t * E_ + threadIdx.x];   // blockDim.x == 256 == E_
    __syncthreads();
    float acc = 0.f;
#pragma unroll 8
    for (int e = 0; e < E_; ++e) acc += er[e] * We[(size_t)e * H_ + h];
    proj[(size_t)t * H_ + h] = acc;
}

// ---------- persistent scan kernel ----------
// 256 blocks, 1/CU. Block (rg=bid&7, cg=bid>>3) owns h rows [rg*32,+32) x cols
// [cg*32,+32). Groups of 32 same-rg blocks are closed dependency sets.
// Exchange via coherence-point bypass (sc0 sc1) loads/stores + device atomics:
// NO threadfence / L2 writeback-invalidate anywhere in the loop, so read-only
// data (proj, WoT, x) stays cache-warm and W_h^T persists in LDS all 512 steps.
__global__ __launch_bounds__(256, 1) void k_scan(
    const int* __restrict__ x, const float* __restrict__ proj,
    const ushort* __restrict__ WhT, const ushort* __restrict__ WoT,
    ushort* __restrict__ ring, float* __restrict__ logits,
    float* __restrict__ final_h, unsigned* __restrict__ flags)
{
    __shared__ ushort lds_w[32 * 1024];   // W_h^T rows c0..c0+32, swizzled (64KB), persistent
    __shared__ ushort lds_h[32 * 1024];   // H_s rows r0..r0+32, swizzled (64KB), per step
    __shared__ float  red[4 * 64 * 4];    // B-phase cross-wave reduce (4KB)
    __shared__ ushort stile[32 * 32];     // A-phase store repack (2KB)

    int tid = threadIdx.x;
    int w = tid >> 6, lane = tid & 63;
    int l15 = lane & 15, l4 = lane >> 4;
    int bid = blockIdx.x;
    int rg = bid & 7;             // row-group (L2-locality heuristic only)
    int cg = bid >> 3;            // 0..31 col-group
    int r0 = rg * 32, c0 = cg * 32;

    // --- preload W slice once via global_load_lds (pre-swizzled source)
    {
        const char* wsrc = (const char*)(WhT + (size_t)c0 * H_);
        char* wd = (char*)lds_w;
        for (int i = 0; i < 16; ++i) {
            int chunk = (w * 16 + i) * 1024;
            int o = chunk + lane * 16;
            int row = o >> 11, b = o & 2047;
            int so = row * 2048 + (b ^ ((row & 7) << 4));
            load_lds16(wsrc + so, wd + chunk);
        }
    }

    // A-phase constants
    int a = w >> 1, bc = w & 1;
    int arow = a * 16 + l15;
    int brow = bc * 16 + l15;
    const char* ha = (const char*)lds_h + arow * 2048;
    const char* wa = (const char*)lds_w + brow * 2048;
    int as = (arow & 7) << 4, bs = (brow & 7) << 4;
    int gcol = c0 + bc * 16 + l15;

    // B-phase constants
    int lrg = cg & 1, vcol0 = (cg >> 1) * 16;
    int srow = lrg * 16 + l15;
    const char* hbp = (const char*)lds_h + srow * 2048;
    int hs2 = (srow & 7) << 4;
    const ushort* wo = WoT + (size_t)(vcol0 + l15) * H_;

    for (int s = 0; s <= L_; ++s) {
        // --- wait for H_s via bypass poll of the device-scope flag
        if (s > 0) {
            if (tid == 0) {
                const unsigned* fp = &flags[rg * 512 + (s - 1)];
                unsigned v;
                do {
                    asm volatile("global_load_dword %0, %1, off sc0 sc1\n\t"
                                 "s_waitcnt vmcnt(0)"
                                 : "=v"(v) : "v"(fp) : "memory");
                    if (v >= 32u) break;
                    __builtin_amdgcn_s_sleep(1);
                } while (1);
            }
        }
        __syncthreads();           // poll done; B-phase (s-1) done reading lds_h

        // --- reg-stage H_s rows [r0,+32) from ring slot s&1 (bypass loads),
        //     then swizzled ds_write_b128: LDS(row,b) = src(row, b^((row&7)<<4))
        {
            const char* hsrc = (const char*)(ring + (size_t)(s & 1) * B_ * H_
                                             + (size_t)r0 * H_) + tid * 16;
            f32x4 tv[16];
#pragma unroll
            for (int i = 0; i < 16; ++i) {
                asm volatile("global_load_dwordx4 %0, %1, off sc0 sc1"
                             : "=v"(tv[i]) : "v"(hsrc + i * 4096) : "memory");
            }
            asm volatile("s_waitcnt vmcnt(0)" ::: "memory");
#pragma unroll
            for (int i = 0; i < 16; ++i) {
                int o = i * 4096 + tid * 16;
                int row = o >> 11, b = o & 2047;
                *(f32x4*)((char*)lds_h + row * 2048 + (b ^ ((row & 7) << 4))) = tv[i];
            }
        }
        __syncthreads();

        // --- A phase: H_{s+1} tile = tanh(proj[x[:,s]] + H_s @ W_h)
        if (s < L_) {
            // hoist gathers above the MFMA chain so their latency hides under it
            float pv[4];
#pragma unroll
            for (int j = 0; j < 4; ++j) {
                int grow = r0 + a * 16 + l4 * 4 + j;
                pv[j] = proj[(size_t)x[grow * L_ + s] * H_ + gcol];
            }
            f32x4 acc = {0.f, 0.f, 0.f, 0.f};
#pragma unroll
            for (int kk = 0; kk < 32; ++kk) {
                int kb = (kk * 32 + l4 * 8) * 2;
                bf16x8 af = *(const bf16x8*)(ha + (kb ^ as));
                bf16x8 bf = *(const bf16x8*)(wa + (kb ^ bs));
                acc = __builtin_amdgcn_mfma_f32_16x16x32_bf16(af, bf, acc, 0, 0, 0);
            }
#pragma unroll
            for (int j = 0; j < 4; ++j) {
                int lrow = a * 16 + l4 * 4 + j;
                float hv = tanhf(acc[j] + pv[j]);
                stile[lrow * 32 + bc * 16 + l15] = f2bf(hv);
                if (s == L_ - 1) final_h[(size_t)(r0 + lrow) * H_ + gcol] = hv;
            }
            __syncthreads();       // stile complete
            // repacked, coalesced 16B write-through stores of the 32x32 tile
            if (tid < 128) {
                int row = tid >> 2, seg = tid & 3;
                f32x4 d = *(const f32x4*)&stile[row * 32 + seg * 8];
                char* dst = (char*)(ring + (size_t)((s + 1) & 1) * B_ * H_
                                    + (size_t)(r0 + row) * H_ + c0 + seg * 8);
                asm volatile("global_store_dwordx4 %0, %1, off sc0 sc1"
                             :: "v"(dst), "v"(d) : "memory");
            }
            asm volatile("s_waitcnt vmcnt(0)" ::: "memory");
            __syncthreads();       // all lanes' stores at coherence point
            if (tid == 0) atomicAdd(&flags[rg * 512 + s], 1u);   // release
        }

        // --- B phase (off critical path): logits[:, s-1] from lds_h = H_s
        if (s > 0) {
            f32x4 lacc = {0.f, 0.f, 0.f, 0.f};
#pragma unroll
            for (int kk = 0; kk < 8; ++kk) {
                int k = w * 256 + kk * 32 + l4 * 8;
                bf16x8 af = *(const bf16x8*)(hbp + ((2 * k) ^ hs2));
                bf16x8 bf = *(const bf16x8*)(wo + k);
                lacc = __builtin_amdgcn_mfma_f32_16x16x32_bf16(af, bf, lacc, 0, 0, 0);
            }
#pragma unroll
            for (int j = 0; j < 4; ++j) red[(w * 64 + lane) * 4 + j] = lacc[j];
            __syncthreads();
            if (w == 0) {
                int growb = r0 + lrg * 16 + l4 * 4;
#pragma unroll
                for (int j = 0; j < 4; ++j) {
                    float ssum = red[(0 * 64 + lane) * 4 + j] + red[(1 * 64 + lane) * 4 + j]
                               + red[(2 * 64 + lane) * 4 + j] + red[(3 * 64 + lane) * 4 + j];
                    logits[((size_t)(growb + j) * L_ + (s - 1)) * V_ + vcol0 + l15] = ssum;
                }
            }
        }
    }
}

extern "C" void kernel_launch(void* const* d_in, const int* in_sizes, int n_in,
                              void* d_out, int out_size, void* d_ws, size_t ws_size,
                              hipStream_t stream)
{
    const int*   x   = (const int*)d_in[0];
    const float* hid = (const float*)d_in[1];
    const float* emb = (const float*)d_in[2];
    const float* We  = (const float*)d_in[3];
    const float* Wh  = (const float*)d_in[4];
    const float* Wo  = (const float*)d_in[5];

    float* logits  = (float*)d_out;                       // [B][L][V] f32
    float* final_h = logits + (size_t)B_ * L_ * V_;       // [B][H] f32

    char* ws = (char*)d_ws;
    float*    proj  = (float*)(ws);                                   // 1 MB   f32 [V][H]
    ushort*   WhT   = (ushort*)(ws + (1u << 20));                     // 2 MB   bf16 [H][H]^T
    ushort*   WoT   = (ushort*)(ws + 3u * (1u << 20));                // 0.5 MB bf16 [V][H]^T
    ushort*   ring  = (ushort*)(ws + 3u * (1u << 20) + (1u << 19));   // 1 MB   bf16 2x[B][H]
    unsigned* flags = (unsigned*)(ws + 4u * (1u << 20) + (1u << 19)); // 16 KB  u32 [8][512]

    // prep (stream-ordered before the persistent kernel)
    k_zero<<<dim3(16), 256, 0, stream>>>(flags, 8 * 512);
    k_transpose_bf16<<<dim3(16, 16), 256, 0, stream>>>(Wh, WhT, H_, H_);
    k_transpose_bf16<<<dim3(4, 16),  256, 0, stream>>>(Wo, WoT, H_, V_);
    k_f32_to_bf16<<<dim3(1024), 256, 0, stream>>>(hid, ring, B_ * H_);   // H_0 -> slot 0
    k_proj<<<dim3(256, 4), 256, 0, stream>>>(emb, We, proj);

    // one persistent kernel does all 512 steps + fused logits
    k_scan<<<dim3(256), 256, 0, stream>>>(x, proj, WhT, WoT, ring,
                                          logits, final_h, flags);
}